// Round 9
// baseline (59.716 us; speedup 1.0000x reference)
//
#include <hip/hip_runtime.h>

#define TPB 256
#define MPW 128               // matrices per tile (per wave)
#define FPW (MPW * 9)         // 1152 floats = 4608 B per tile buffer
#define F4PW (FPW / 4)        // 288 float4 per tile

typedef float v2f __attribute__((ext_vector_type(2)));
typedef int   v2i __attribute__((ext_vector_type(2)));

static __device__ __forceinline__ v2f sqrt2(v2f a){
    v2f r; r.x = __builtin_amdgcn_sqrtf(a.x); r.y = __builtin_amdgcn_sqrtf(a.y); return r;
}
static __device__ __forceinline__ v2f rsq2(v2f a){
    v2f r; r.x = __builtin_amdgcn_rsqf(a.x); r.y = __builtin_amdgcn_rsqf(a.y); return r;
}
static __device__ __forceinline__ v2f csign2(v2f x, v2f y){
    v2f r; r.x = copysignf(x.x, y.x); r.y = copysignf(x.y, y.y); return r;
}
static __device__ __forceinline__ v2f fabs2(v2f x){
    v2f r; r.x = fabsf(x.x); r.y = fabsf(x.y); return r;
}
static __device__ __forceinline__ v2f sel2(v2i m, v2f a, v2f b){
    v2f r; r.x = m.x ? a.x : b.x; r.y = m.y ? a.y : b.y; return r;
}
static __device__ __forceinline__ void rot2(v2f &p, v2f &q, v2f c, v2f s){
    v2f x = p, y = q; p = c*x - s*y; q = s*x + c*y;
}

// Exact cyclic-Jacobi rotation (2 transcendentals), branchless. (unchanged)
static __device__ __forceinline__ void jrot2(v2f &app, v2f &aqq, v2f &apq,
                                             v2f &arp, v2f &arq,
                                             v2f &v0p, v2f &v1p, v2f &v2p,
                                             v2f &v0q, v2f &v1q, v2f &v2q)
{
    v2f d   = aqq - app;
    v2f w   = apq + apq;
    v2f nrm = d*d + w*w;
    v2f rr  = sqrt2(nrm);
    v2f sr  = csign2(rr, d);
    v2f den = d + sr;
    v2f inv = rsq2(den*den + w*w);
    v2f c   = fabs2(den) * inv;
    v2f s   = w * csign2(inv, den);
    v2i tiny = nrm < (v2f)1e-30f;
    c = sel2(tiny, (v2f)1.0f, c);
    s = sel2(tiny, (v2f)0.0f, s);
    v2f sum = app + aqq;
    v2f lo  = 0.5f*(sum - sr);
    app = lo; aqq = sum - lo; apq = (v2f)0.0f;
    rot2(arp, arq, c, s);
    rot2(v0p, v0q, c, s);
    rot2(v1p, v1q, c, s);
    rot2(v2p, v2q, c, s);
}

// SO(3) projection for 2 packed matrices (round-7 version, verified):
// V from 3 Jacobi sweeps; U via Gram-Schmidt on b1,b2 + u3 = u1 x u2.
static __device__ __forceinline__ void solve2(
    v2f m00, v2f m01, v2f m02,
    v2f m10, v2f m11, v2f m12,
    v2f m20, v2f m21, v2f m22,
    v2f &r00, v2f &r01, v2f &r02,
    v2f &r10, v2f &r11, v2f &r12,
    v2f &r20, v2f &r21, v2f &r22)
{
    v2f a00 = m00*m00 + m10*m10 + m20*m20;
    v2f a11 = m01*m01 + m11*m11 + m21*m21;
    v2f a22 = m02*m02 + m12*m12 + m22*m22;
    v2f a01 = m00*m01 + m10*m11 + m20*m21;
    v2f a02 = m00*m02 + m10*m12 + m20*m22;
    v2f a12 = m01*m02 + m11*m12 + m21*m22;

    v2f v00 = (v2f)1.0f, v01 = (v2f)0.0f, v02 = (v2f)0.0f;
    v2f v10 = (v2f)0.0f, v11 = (v2f)1.0f, v12 = (v2f)0.0f;
    v2f v20 = (v2f)0.0f, v21 = (v2f)0.0f, v22 = (v2f)1.0f;

    #pragma unroll
    for (int sw = 0; sw < 3; ++sw) {
        jrot2(a00, a11, a01, a02, a12, v00, v10, v20, v01, v11, v21);
        jrot2(a00, a22, a02, a01, a12, v00, v10, v20, v02, v12, v22);
        jrot2(a11, a22, a12, a01, a02, v01, v11, v21, v02, v12, v22);
    }

    v2f t;
    {
        v2i c01 = a00 < a11;
        t = a00; a00 = sel2(c01, a11, a00); a11 = sel2(c01, t, a11);
        t = v00; v00 = sel2(c01, v01, v00); v01 = sel2(c01, -t, v01);
        t = v10; v10 = sel2(c01, v11, v10); v11 = sel2(c01, -t, v11);
        t = v20; v20 = sel2(c01, v21, v20); v21 = sel2(c01, -t, v21);
    }
    {
        v2i c02 = a00 < a22;
        t = a00; a00 = sel2(c02, a22, a00); a22 = sel2(c02, t, a22);
        t = v00; v00 = sel2(c02, v02, v00); v02 = sel2(c02, -t, v02);
        t = v10; v10 = sel2(c02, v12, v10); v12 = sel2(c02, -t, v12);
        t = v20; v20 = sel2(c02, v22, v20); v22 = sel2(c02, -t, v22);
    }
    {
        v2i c12 = a11 < a22;
        t = a11; a11 = sel2(c12, a22, a11); a22 = sel2(c12, t, a22);
        t = v01; v01 = sel2(c12, v02, v01); v02 = sel2(c12, -t, v02);
        t = v11; v11 = sel2(c12, v12, v11); v12 = sel2(c12, -t, v12);
        t = v21; v21 = sel2(c12, v22, v21); v22 = sel2(c12, -t, v22);
    }

    v2f b00 = m00*v00 + m01*v10 + m02*v20;
    v2f b10 = m10*v00 + m11*v10 + m12*v20;
    v2f b20 = m20*v00 + m21*v10 + m22*v20;
    v2f b01 = m00*v01 + m01*v11 + m02*v21;
    v2f b11 = m10*v01 + m11*v11 + m12*v21;
    v2f b21 = m20*v01 + m21*v11 + m22*v21;

    v2f n1 = b00*b00 + b10*b10 + b20*b20;
    v2f i1 = rsq2(n1);
    v2i ok1 = n1 > (v2f)1e-30f;
    i1 = sel2(ok1, i1, (v2f)0.0f);
    v2f u00 = b00*i1, u10 = b10*i1, u20 = b20*i1;

    v2f d12 = b01*u00 + b11*u10 + b21*u20;
    v2f q0 = b01 - d12*u00;
    v2f q1 = b11 - d12*u10;
    v2f q2 = b21 - d12*u20;
    v2f n2 = q0*q0 + q1*q1 + q2*q2;
    v2f i2 = rsq2(n2);
    v2i ok2 = n2 > (v2f)1e-30f;
    i2 = sel2(ok2, i2, (v2f)0.0f);
    v2f u01 = q0*i2, u11 = q1*i2, u21 = q2*i2;

    v2f u02 = u10*u21 - u20*u11;
    v2f u12 = u20*u01 - u00*u21;
    v2f u22 = u00*u11 - u10*u01;

    r00 = u00*v00 + u01*v01 + u02*v02;
    r01 = u00*v10 + u01*v11 + u02*v12;
    r02 = u00*v20 + u01*v21 + u02*v22;
    r10 = u10*v00 + u11*v01 + u12*v02;
    r11 = u10*v10 + u11*v11 + u12*v12;
    r12 = u10*v20 + u11*v21 + u12*v22;
    r20 = u20*v00 + u21*v01 + u22*v02;
    r21 = u20*v10 + u21*v11 + u22*v12;
    r22 = u20*v20 + u21*v21 + u22*v22;
}

static __device__ __forceinline__ float4 ld_f4(const float* __restrict__ x, long f, long ntotf){
    if (f + 4 <= ntotf) return *(const float4*)(x + f);
    float4 r = make_float4(0.f, 0.f, 0.f, 0.f);
    if (f     < ntotf) r.x = x[f];
    if (f + 1 < ntotf) r.y = x[f + 1];
    if (f + 2 < ntotf) r.z = x[f + 2];
    if (f + 3 < ntotf) r.w = x[f + 3];
    return r;
}
static __device__ __forceinline__ void st_f4(float* __restrict__ o, long f, float4 v, long ntotf){
    if (f + 4 <= ntotf) { *(float4*)(o + f) = v; return; }
    if (f     < ntotf) o[f]     = v.x;
    if (f + 1 < ntotf) o[f + 1] = v.y;
    if (f + 2 < ntotf) o[f + 2] = v.z;
    if (f + 3 < ntotf) o[f + 3] = v.w;
}

// Wave-local SINGLE-buffer persistent pipeline. Correctness of single buffer:
// DS ops from one wave are processed by the LDS pipeline IN ORDER, so
// iteration k's store-phase ds_reads always complete before iteration k+1's
// landing ds_writes to the same addresses. The prefetched tile lives in the
// q registers (not LDS) across compute, so no second buffer is needed.
// 18432 B/block -> 8 blocks/CU; __launch_bounds__(256,8) caps VGPR at 64 ->
// 32 waves/CU (2x round 8's TLP). No __syncthreads anywhere.
__global__ __launch_bounds__(TPB, 8) void svdo_kernel(const float* __restrict__ x,
                                                      float* __restrict__ out,
                                                      int nmat, int ntiles, int W)
{
    __shared__ float lds[4][FPW];       // 18432 B
    const int lane = threadIdx.x & 63;
    const int wv   = threadIdx.x >> 6;
    const long ntotf = (long)nmat * 9;

    int tile = blockIdx.x * 4 + wv;
    if (tile >= ntiles) return;

    float* L = lds[wv];

    float4 q0, q1, q2, q3, q4;
    {   // prologue: issue loads for first tile
        const long fb = (long)tile * FPW;
        q0 = ld_f4(x, fb + (long)(lane       ) * 4, ntotf);
        q1 = ld_f4(x, fb + (long)(lane +  64) * 4, ntotf);
        q2 = ld_f4(x, fb + (long)(lane + 128) * 4, ntotf);
        q3 = ld_f4(x, fb + (long)(lane + 192) * 4, ntotf);
        q4 = make_float4(0.f, 0.f, 0.f, 0.f);
        if (lane < 32) q4 = ld_f4(x, fb + (long)(lane + 256) * 4, ntotf);
    }

    for (;;) {
        // Land prefetched tile (counted vmcnt wait on the loads only; older
        // stores from iter k-1 keep draining in background).
        *(float4*)&L[(lane       ) * 4] = q0;
        *(float4*)&L[(lane +  64) * 4] = q1;
        *(float4*)&L[(lane + 128) * 4] = q2;
        *(float4*)&L[(lane + 192) * 4] = q3;
        if (lane < 32) *(float4*)&L[(lane + 256) * 4] = q4;
        asm volatile("s_waitcnt lgkmcnt(0)" ::: "memory");

        const int  nxt  = tile + W;
        const bool have = nxt < ntiles;
        if (have) {   // issue next tile's loads — in flight under compute
            const long fb = (long)nxt * FPW;
            q0 = ld_f4(x, fb + (long)(lane       ) * 4, ntotf);
            q1 = ld_f4(x, fb + (long)(lane +  64) * 4, ntotf);
            q2 = ld_f4(x, fb + (long)(lane + 128) * 4, ntotf);
            q3 = ld_f4(x, fb + (long)(lane + 192) * 4, ntotf);
            if (lane < 32) q4 = ld_f4(x, fb + (long)(lane + 256) * 4, ntotf);
        }

        // Compute 2 matrices (stride-9 LDS reads: 2 lanes/bank, free).
        {
            const float* p0 = &L[lane * 9];
            const float* p1 = &L[(lane + 64) * 9];
            v2f m00 = {p0[0], p1[0]}, m01 = {p0[1], p1[1]}, m02 = {p0[2], p1[2]};
            v2f m10 = {p0[3], p1[3]}, m11 = {p0[4], p1[4]}, m12 = {p0[5], p1[5]};
            v2f m20 = {p0[6], p1[6]}, m21 = {p0[7], p1[7]}, m22 = {p0[8], p1[8]};

            v2f r00, r01, r02, r10, r11, r12, r20, r21, r22;
            solve2(m00, m01, m02, m10, m11, m12, m20, m21, m22,
                   r00, r01, r02, r10, r11, r12, r20, r21, r22);

            float* o0 = &L[lane * 9];
            o0[0]=r00.x; o0[1]=r01.x; o0[2]=r02.x;
            o0[3]=r10.x; o0[4]=r11.x; o0[5]=r12.x;
            o0[6]=r20.x; o0[7]=r21.x; o0[8]=r22.x;
            float* o1 = &L[(lane + 64) * 9];
            o1[0]=r00.y; o1[1]=r01.y; o1[2]=r02.y;
            o1[3]=r10.y; o1[4]=r11.y; o1[5]=r12.y;
            o1[6]=r20.y; o1[7]=r21.y; o1[8]=r22.y;
        }
        asm volatile("s_waitcnt lgkmcnt(0)" ::: "memory");

        // Coalesced stores (fire-and-forget).
        {
            const long fb = (long)tile * FPW;
            st_f4(out, fb + (long)(lane       ) * 4, *(const float4*)&L[(lane       ) * 4], ntotf);
            st_f4(out, fb + (long)(lane +  64) * 4, *(const float4*)&L[(lane +  64) * 4], ntotf);
            st_f4(out, fb + (long)(lane + 128) * 4, *(const float4*)&L[(lane + 128) * 4], ntotf);
            st_f4(out, fb + (long)(lane + 192) * 4, *(const float4*)&L[(lane + 192) * 4], ntotf);
            if (lane < 32)
                st_f4(out, fb + (long)(lane + 256) * 4, *(const float4*)&L[(lane + 256) * 4], ntotf);
        }

        if (!have) break;
        tile = nxt;
    }
}

extern "C" void kernel_launch(void* const* d_in, const int* in_sizes, int n_in,
                              void* d_out, int out_size, void* d_ws, size_t ws_size,
                              hipStream_t stream)
{
    (void)n_in; (void)d_ws; (void)ws_size; (void)out_size;
    const float* x = (const float*)d_in[0];
    float* out = (float*)d_out;
    const int nmat = in_sizes[0] / 9;
    const int ntiles = (nmat + MPW - 1) / MPW;
    int grid = (ntiles + 3) / 4;
    if (grid > 2048) grid = 2048;   // 8 blocks/CU x 256 CU -> chip exactly full
    const int W = grid * 4;         // total waves = tile stride
    svdo_kernel<<<grid, TPB, 0, stream>>>(x, out, nmat, ntiles, W);
}

// Round 10
// 46.045 us; speedup vs baseline: 1.2969x; 1.2969x over previous
//
#include <hip/hip_runtime.h>

#define TPB 256
#define MPW 128               // matrices per tile (per wave)
#define FPW (MPW * 9)         // 1152 floats = 4608 B per tile buffer

typedef float v2f __attribute__((ext_vector_type(2)));
typedef int   v2i __attribute__((ext_vector_type(2)));

static __device__ __forceinline__ v2f sqrt2(v2f a){
    v2f r; r.x = __builtin_amdgcn_sqrtf(a.x); r.y = __builtin_amdgcn_sqrtf(a.y); return r;
}
static __device__ __forceinline__ v2f rsq2(v2f a){
    v2f r; r.x = __builtin_amdgcn_rsqf(a.x); r.y = __builtin_amdgcn_rsqf(a.y); return r;
}
static __device__ __forceinline__ v2f csign2(v2f x, v2f y){
    v2f r; r.x = copysignf(x.x, y.x); r.y = copysignf(x.y, y.y); return r;
}
static __device__ __forceinline__ v2f fabs2(v2f x){
    v2f r; r.x = fabsf(x.x); r.y = fabsf(x.y); return r;
}
static __device__ __forceinline__ v2f sel2(v2i m, v2f a, v2f b){
    v2f r; r.x = m.x ? a.x : b.x; r.y = m.y ? a.y : b.y; return r;
}
static __device__ __forceinline__ void rot2(v2f &p, v2f &q, v2f c, v2f s){
    v2f x = p, y = q; p = c*x - s*y; q = s*x + c*y;
}

// Exact cyclic-Jacobi rotation (2 transcendentals), branchless. (unchanged)
static __device__ __forceinline__ void jrot2(v2f &app, v2f &aqq, v2f &apq,
                                             v2f &arp, v2f &arq,
                                             v2f &v0p, v2f &v1p, v2f &v2p,
                                             v2f &v0q, v2f &v1q, v2f &v2q)
{
    v2f d   = aqq - app;
    v2f w   = apq + apq;
    v2f nrm = d*d + w*w;
    v2f rr  = sqrt2(nrm);
    v2f sr  = csign2(rr, d);
    v2f den = d + sr;
    v2f inv = rsq2(den*den + w*w);
    v2f c   = fabs2(den) * inv;
    v2f s   = w * csign2(inv, den);
    v2i tiny = nrm < (v2f)1e-30f;
    c = sel2(tiny, (v2f)1.0f, c);
    s = sel2(tiny, (v2f)0.0f, s);
    v2f sum = app + aqq;
    v2f lo  = 0.5f*(sum - sr);
    app = lo; aqq = sum - lo; apq = (v2f)0.0f;
    rot2(arp, arq, c, s);
    rot2(v0p, v0q, c, s);
    rot2(v1p, v1q, c, s);
    rot2(v2p, v2q, c, s);
}

// SO(3) projection for 2 packed matrices (round-7 version, verified):
// V from 3 Jacobi sweeps; U via Gram-Schmidt on b1,b2 + u3 = u1 x u2.
static __device__ __forceinline__ void solve2(
    v2f m00, v2f m01, v2f m02,
    v2f m10, v2f m11, v2f m12,
    v2f m20, v2f m21, v2f m22,
    v2f &r00, v2f &r01, v2f &r02,
    v2f &r10, v2f &r11, v2f &r12,
    v2f &r20, v2f &r21, v2f &r22)
{
    v2f a00 = m00*m00 + m10*m10 + m20*m20;
    v2f a11 = m01*m01 + m11*m11 + m21*m21;
    v2f a22 = m02*m02 + m12*m12 + m22*m22;
    v2f a01 = m00*m01 + m10*m11 + m20*m21;
    v2f a02 = m00*m02 + m10*m12 + m20*m22;
    v2f a12 = m01*m02 + m11*m12 + m21*m22;

    v2f v00 = (v2f)1.0f, v01 = (v2f)0.0f, v02 = (v2f)0.0f;
    v2f v10 = (v2f)0.0f, v11 = (v2f)1.0f, v12 = (v2f)0.0f;
    v2f v20 = (v2f)0.0f, v21 = (v2f)0.0f, v22 = (v2f)1.0f;

    #pragma unroll
    for (int sw = 0; sw < 3; ++sw) {
        jrot2(a00, a11, a01, a02, a12, v00, v10, v20, v01, v11, v21);
        jrot2(a00, a22, a02, a01, a12, v00, v10, v20, v02, v12, v22);
        jrot2(a11, a22, a12, a01, a02, v01, v11, v21, v02, v12, v22);
    }

    v2f t;
    {
        v2i c01 = a00 < a11;
        t = a00; a00 = sel2(c01, a11, a00); a11 = sel2(c01, t, a11);
        t = v00; v00 = sel2(c01, v01, v00); v01 = sel2(c01, -t, v01);
        t = v10; v10 = sel2(c01, v11, v10); v11 = sel2(c01, -t, v11);
        t = v20; v20 = sel2(c01, v21, v20); v21 = sel2(c01, -t, v21);
    }
    {
        v2i c02 = a00 < a22;
        t = a00; a00 = sel2(c02, a22, a00); a22 = sel2(c02, t, a22);
        t = v00; v00 = sel2(c02, v02, v00); v02 = sel2(c02, -t, v02);
        t = v10; v10 = sel2(c02, v12, v10); v12 = sel2(c02, -t, v12);
        t = v20; v20 = sel2(c02, v22, v20); v22 = sel2(c02, -t, v22);
    }
    {
        v2i c12 = a11 < a22;
        t = a11; a11 = sel2(c12, a22, a11); a22 = sel2(c12, t, a22);
        t = v01; v01 = sel2(c12, v02, v01); v02 = sel2(c12, -t, v02);
        t = v11; v11 = sel2(c12, v12, v11); v12 = sel2(c12, -t, v12);
        t = v21; v21 = sel2(c12, v22, v21); v22 = sel2(c12, -t, v22);
    }

    v2f b00 = m00*v00 + m01*v10 + m02*v20;
    v2f b10 = m10*v00 + m11*v10 + m12*v20;
    v2f b20 = m20*v00 + m21*v10 + m22*v20;
    v2f b01 = m00*v01 + m01*v11 + m02*v21;
    v2f b11 = m10*v01 + m11*v11 + m12*v21;
    v2f b21 = m20*v01 + m21*v11 + m22*v21;

    v2f n1 = b00*b00 + b10*b10 + b20*b20;
    v2f i1 = rsq2(n1);
    v2i ok1 = n1 > (v2f)1e-30f;
    i1 = sel2(ok1, i1, (v2f)0.0f);
    v2f u00 = b00*i1, u10 = b10*i1, u20 = b20*i1;

    v2f d12 = b01*u00 + b11*u10 + b21*u20;
    v2f q0 = b01 - d12*u00;
    v2f q1 = b11 - d12*u10;
    v2f q2 = b21 - d12*u20;
    v2f n2 = q0*q0 + q1*q1 + q2*q2;
    v2f i2 = rsq2(n2);
    v2i ok2 = n2 > (v2f)1e-30f;
    i2 = sel2(ok2, i2, (v2f)0.0f);
    v2f u01 = q0*i2, u11 = q1*i2, u21 = q2*i2;

    v2f u02 = u10*u21 - u20*u11;
    v2f u12 = u20*u01 - u00*u21;
    v2f u22 = u00*u11 - u10*u01;

    r00 = u00*v00 + u01*v01 + u02*v02;
    r01 = u00*v10 + u01*v11 + u02*v12;
    r02 = u00*v20 + u01*v21 + u02*v22;
    r10 = u10*v00 + u11*v01 + u12*v02;
    r11 = u10*v10 + u11*v11 + u12*v12;
    r12 = u10*v20 + u11*v21 + u12*v22;
    r20 = u20*v00 + u21*v01 + u22*v02;
    r21 = u20*v10 + u21*v11 + u22*v12;
    r22 = u20*v20 + u21*v21 + u22*v22;
}

static __device__ __forceinline__ float4 ld_f4g(const float* __restrict__ x, int f, int ntotf){
    if (f + 4 <= ntotf) return *(const float4*)(x + f);
    float4 r = make_float4(0.f, 0.f, 0.f, 0.f);
    if (f     < ntotf) r.x = x[f];
    if (f + 1 < ntotf) r.y = x[f + 1];
    if (f + 2 < ntotf) r.z = x[f + 2];
    if (f + 3 < ntotf) r.w = x[f + 3];
    return r;
}
static __device__ __forceinline__ float2 ld_f2g(const float* __restrict__ x, int f, int ntotf){
    if (f + 2 <= ntotf) return *(const float2*)(x + f);
    float2 r = make_float2(0.f, 0.f);
    if (f < ntotf) r.x = x[f];
    return r;
}
static __device__ __forceinline__ void st_f4g(float* __restrict__ o, int f, float4 v, int ntotf){
    if (f + 4 <= ntotf) { *(float4*)(o + f) = v; return; }
    if (f     < ntotf) o[f]     = v.x;
    if (f + 1 < ntotf) o[f + 1] = v.y;
    if (f + 2 < ntotf) o[f + 2] = v.z;
    if (f + 3 < ntotf) o[f + 3] = v.w;
}
static __device__ __forceinline__ void st_f2g(float* __restrict__ o, int f, float2 v, int ntotf){
    if (f + 2 <= ntotf) { *(float2*)(o + f) = v; return; }
    if (f < ntotf) o[f] = v.x;
}

// Wave-local SINGLE-buffer persistent pipeline (r9 structure, r8-safe VGPRs).
// Single buffer is correct: the per-wave DS pipe is in-order, so iteration
// k's store-phase ds_reads complete before iteration k+1's landing ds_writes
// to the same addresses; the prefetched tile lives in q registers meanwhile.
// Per-lane tile slice = 4 x float4 + 1 x float2 = 72 B (uniform, no masked
// fifth op). __launch_bounds__(256,6): VGPR cap ~85 (need ~70 -> no spill),
// 18.4 KB LDS -> 6 blocks/CU resident -> 24 waves/CU.
template<bool EXACT>
__global__ __launch_bounds__(TPB, 6) void svdo_kernel(const float* __restrict__ x,
                                                      float* __restrict__ out,
                                                      int nmat, int ntiles, int W)
{
    __shared__ float lds[4][FPW];       // 18432 B / block
    const int lane = threadIdx.x & 63;
    const int wv   = threadIdx.x >> 6;
    const int ntotf = nmat * 9;

    int tile = blockIdx.x * 4 + wv;
    if (tile >= ntiles) return;

    float* L = lds[wv];

    float4 q0, q1, q2, q3;
    float2 q4;
    {   // prologue: issue loads for first tile
        const int fb = tile * FPW;
        if (EXACT) {
            q0 = *(const float4*)(x + fb + (lane       ) * 4);
            q1 = *(const float4*)(x + fb + (lane +  64) * 4);
            q2 = *(const float4*)(x + fb + (lane + 128) * 4);
            q3 = *(const float4*)(x + fb + (lane + 192) * 4);
            q4 = *(const float2*)(x + fb + 1024 + lane * 2);
        } else {
            q0 = ld_f4g(x, fb + (lane       ) * 4, ntotf);
            q1 = ld_f4g(x, fb + (lane +  64) * 4, ntotf);
            q2 = ld_f4g(x, fb + (lane + 128) * 4, ntotf);
            q3 = ld_f4g(x, fb + (lane + 192) * 4, ntotf);
            q4 = ld_f2g(x, fb + 1024 + lane * 2, ntotf);
        }
    }

    for (;;) {
        // Land prefetched tile (counted vmcnt wait on loads only).
        *(float4*)&L[(lane       ) * 4] = q0;
        *(float4*)&L[(lane +  64) * 4] = q1;
        *(float4*)&L[(lane + 128) * 4] = q2;
        *(float4*)&L[(lane + 192) * 4] = q3;
        *(float2*)&L[1024 + lane * 2]  = q4;
        asm volatile("s_waitcnt lgkmcnt(0)" ::: "memory");

        const int  nxt  = tile + W;
        const bool have = nxt < ntiles;
        if (have) {   // issue next tile's loads — in flight under compute
            const int fb = nxt * FPW;
            if (EXACT) {
                q0 = *(const float4*)(x + fb + (lane       ) * 4);
                q1 = *(const float4*)(x + fb + (lane +  64) * 4);
                q2 = *(const float4*)(x + fb + (lane + 128) * 4);
                q3 = *(const float4*)(x + fb + (lane + 192) * 4);
                q4 = *(const float2*)(x + fb + 1024 + lane * 2);
            } else {
                q0 = ld_f4g(x, fb + (lane       ) * 4, ntotf);
                q1 = ld_f4g(x, fb + (lane +  64) * 4, ntotf);
                q2 = ld_f4g(x, fb + (lane + 128) * 4, ntotf);
                q3 = ld_f4g(x, fb + (lane + 192) * 4, ntotf);
                q4 = ld_f2g(x, fb + 1024 + lane * 2, ntotf);
            }
        }

        // Compute 2 matrices (stride-9 LDS reads: 2 lanes/bank, free).
        {
            const float* p0 = &L[lane * 9];
            const float* p1 = &L[(lane + 64) * 9];
            v2f m00 = {p0[0], p1[0]}, m01 = {p0[1], p1[1]}, m02 = {p0[2], p1[2]};
            v2f m10 = {p0[3], p1[3]}, m11 = {p0[4], p1[4]}, m12 = {p0[5], p1[5]};
            v2f m20 = {p0[6], p1[6]}, m21 = {p0[7], p1[7]}, m22 = {p0[8], p1[8]};

            v2f r00, r01, r02, r10, r11, r12, r20, r21, r22;
            solve2(m00, m01, m02, m10, m11, m12, m20, m21, m22,
                   r00, r01, r02, r10, r11, r12, r20, r21, r22);

            float* o0 = &L[lane * 9];
            o0[0]=r00.x; o0[1]=r01.x; o0[2]=r02.x;
            o0[3]=r10.x; o0[4]=r11.x; o0[5]=r12.x;
            o0[6]=r20.x; o0[7]=r21.x; o0[8]=r22.x;
            float* o1 = &L[(lane + 64) * 9];
            o1[0]=r00.y; o1[1]=r01.y; o1[2]=r02.y;
            o1[3]=r10.y; o1[4]=r11.y; o1[5]=r12.y;
            o1[6]=r20.y; o1[7]=r21.y; o1[8]=r22.y;
        }
        asm volatile("s_waitcnt lgkmcnt(0)" ::: "memory");

        // Coalesced stores (fire-and-forget).
        {
            const int fb = tile * FPW;
            if (EXACT) {
                *(float4*)(out + fb + (lane       ) * 4) = *(const float4*)&L[(lane       ) * 4];
                *(float4*)(out + fb + (lane +  64) * 4) = *(const float4*)&L[(lane +  64) * 4];
                *(float4*)(out + fb + (lane + 128) * 4) = *(const float4*)&L[(lane + 128) * 4];
                *(float4*)(out + fb + (lane + 192) * 4) = *(const float4*)&L[(lane + 192) * 4];
                *(float2*)(out + fb + 1024 + lane * 2)  = *(const float2*)&L[1024 + lane * 2];
            } else {
                st_f4g(out, fb + (lane       ) * 4, *(const float4*)&L[(lane       ) * 4], ntotf);
                st_f4g(out, fb + (lane +  64) * 4, *(const float4*)&L[(lane +  64) * 4], ntotf);
                st_f4g(out, fb + (lane + 128) * 4, *(const float4*)&L[(lane + 128) * 4], ntotf);
                st_f4g(out, fb + (lane + 192) * 4, *(const float4*)&L[(lane + 192) * 4], ntotf);
                st_f2g(out, fb + 1024 + lane * 2,  *(const float2*)&L[1024 + lane * 2],  ntotf);
            }
        }

        if (!have) break;
        tile = nxt;
    }
}

extern "C" void kernel_launch(void* const* d_in, const int* in_sizes, int n_in,
                              void* d_out, int out_size, void* d_ws, size_t ws_size,
                              hipStream_t stream)
{
    (void)n_in; (void)d_ws; (void)ws_size; (void)out_size;
    const float* x = (const float*)d_in[0];
    float* out = (float*)d_out;
    const int nmat = in_sizes[0] / 9;
    const int ntiles = (nmat + MPW - 1) / MPW;
    int grid = (ntiles + 3) / 4;
    if (grid > 1536) grid = 1536;   // 6 blocks/CU x 256 CU = exactly resident
    const int W = grid * 4;         // total waves = tile stride
    if (nmat % MPW == 0)
        svdo_kernel<true><<<grid, TPB, 0, stream>>>(x, out, nmat, ntiles, W);
    else
        svdo_kernel<false><<<grid, TPB, 0, stream>>>(x, out, nmat, ntiles, W);
}

// Round 11
// 33.065 us; speedup vs baseline: 1.8060x; 1.3926x over previous
//
#include <hip/hip_runtime.h>

#define TPB 256
#define MPW 128               // matrices per tile (per wave)
#define FPW (MPW * 9)         // 1152 floats = 4608 B per tile buffer

typedef float v2f __attribute__((ext_vector_type(2)));
typedef int   v2i __attribute__((ext_vector_type(2)));

static __device__ __forceinline__ v2f sqrt2(v2f a){
    v2f r; r.x = __builtin_amdgcn_sqrtf(a.x); r.y = __builtin_amdgcn_sqrtf(a.y); return r;
}
static __device__ __forceinline__ v2f rsq2(v2f a){
    v2f r; r.x = __builtin_amdgcn_rsqf(a.x); r.y = __builtin_amdgcn_rsqf(a.y); return r;
}
static __device__ __forceinline__ v2f csign2(v2f x, v2f y){
    v2f r; r.x = copysignf(x.x, y.x); r.y = copysignf(x.y, y.y); return r;
}
static __device__ __forceinline__ v2f fabs2(v2f x){
    v2f r; r.x = fabsf(x.x); r.y = fabsf(x.y); return r;
}
static __device__ __forceinline__ v2f sel2(v2i m, v2f a, v2f b){
    v2f r; r.x = m.x ? a.x : b.x; r.y = m.y ? a.y : b.y; return r;
}
static __device__ __forceinline__ void rot2(v2f &p, v2f &q, v2f c, v2f s){
    v2f x = p, y = q; p = c*x - s*y; q = s*x + c*y;
}

// Exact cyclic-Jacobi rotation (2 transcendentals), branchless. (unchanged)
static __device__ __forceinline__ void jrot2(v2f &app, v2f &aqq, v2f &apq,
                                             v2f &arp, v2f &arq,
                                             v2f &v0p, v2f &v1p, v2f &v2p,
                                             v2f &v0q, v2f &v1q, v2f &v2q)
{
    v2f d   = aqq - app;
    v2f w   = apq + apq;
    v2f nrm = d*d + w*w;
    v2f rr  = sqrt2(nrm);
    v2f sr  = csign2(rr, d);
    v2f den = d + sr;
    v2f inv = rsq2(den*den + w*w);
    v2f c   = fabs2(den) * inv;
    v2f s   = w * csign2(inv, den);
    v2i tiny = nrm < (v2f)1e-30f;
    c = sel2(tiny, (v2f)1.0f, c);
    s = sel2(tiny, (v2f)0.0f, s);
    v2f sum = app + aqq;
    v2f lo  = 0.5f*(sum - sr);
    app = lo; aqq = sum - lo; apq = (v2f)0.0f;
    rot2(arp, arq, c, s);
    rot2(v0p, v0q, c, s);
    rot2(v1p, v1q, c, s);
    rot2(v2p, v2q, c, s);
}

// SO(3) projection for 2 packed matrices (round-7 version, verified):
// V from 3 Jacobi sweeps; U via Gram-Schmidt on b1,b2 + u3 = u1 x u2.
static __device__ __forceinline__ void solve2(
    v2f m00, v2f m01, v2f m02,
    v2f m10, v2f m11, v2f m12,
    v2f m20, v2f m21, v2f m22,
    v2f &r00, v2f &r01, v2f &r02,
    v2f &r10, v2f &r11, v2f &r12,
    v2f &r20, v2f &r21, v2f &r22)
{
    v2f a00 = m00*m00 + m10*m10 + m20*m20;
    v2f a11 = m01*m01 + m11*m11 + m21*m21;
    v2f a22 = m02*m02 + m12*m12 + m22*m22;
    v2f a01 = m00*m01 + m10*m11 + m20*m21;
    v2f a02 = m00*m02 + m10*m12 + m20*m22;
    v2f a12 = m01*m02 + m11*m12 + m21*m22;

    v2f v00 = (v2f)1.0f, v01 = (v2f)0.0f, v02 = (v2f)0.0f;
    v2f v10 = (v2f)0.0f, v11 = (v2f)1.0f, v12 = (v2f)0.0f;
    v2f v20 = (v2f)0.0f, v21 = (v2f)0.0f, v22 = (v2f)1.0f;

    #pragma unroll
    for (int sw = 0; sw < 3; ++sw) {
        jrot2(a00, a11, a01, a02, a12, v00, v10, v20, v01, v11, v21);
        jrot2(a00, a22, a02, a01, a12, v00, v10, v20, v02, v12, v22);
        jrot2(a11, a22, a12, a01, a02, v01, v11, v21, v02, v12, v22);
    }

    v2f t;
    {
        v2i c01 = a00 < a11;
        t = a00; a00 = sel2(c01, a11, a00); a11 = sel2(c01, t, a11);
        t = v00; v00 = sel2(c01, v01, v00); v01 = sel2(c01, -t, v01);
        t = v10; v10 = sel2(c01, v11, v10); v11 = sel2(c01, -t, v11);
        t = v20; v20 = sel2(c01, v21, v20); v21 = sel2(c01, -t, v21);
    }
    {
        v2i c02 = a00 < a22;
        t = a00; a00 = sel2(c02, a22, a00); a22 = sel2(c02, t, a22);
        t = v00; v00 = sel2(c02, v02, v00); v02 = sel2(c02, -t, v02);
        t = v10; v10 = sel2(c02, v12, v10); v12 = sel2(c02, -t, v12);
        t = v20; v20 = sel2(c02, v22, v20); v22 = sel2(c02, -t, v22);
    }
    {
        v2i c12 = a11 < a22;
        t = a11; a11 = sel2(c12, a22, a11); a22 = sel2(c12, t, a22);
        t = v01; v01 = sel2(c12, v02, v01); v02 = sel2(c12, -t, v02);
        t = v11; v11 = sel2(c12, v12, v11); v12 = sel2(c12, -t, v12);
        t = v21; v21 = sel2(c12, v22, v21); v22 = sel2(c12, -t, v22);
    }

    v2f b00 = m00*v00 + m01*v10 + m02*v20;
    v2f b10 = m10*v00 + m11*v10 + m12*v20;
    v2f b20 = m20*v00 + m21*v10 + m22*v20;
    v2f b01 = m00*v01 + m01*v11 + m02*v21;
    v2f b11 = m10*v01 + m11*v11 + m12*v21;
    v2f b21 = m20*v01 + m21*v11 + m22*v21;

    v2f n1 = b00*b00 + b10*b10 + b20*b20;
    v2f i1 = rsq2(n1);
    v2i ok1 = n1 > (v2f)1e-30f;
    i1 = sel2(ok1, i1, (v2f)0.0f);
    v2f u00 = b00*i1, u10 = b10*i1, u20 = b20*i1;

    v2f d12 = b01*u00 + b11*u10 + b21*u20;
    v2f q0 = b01 - d12*u00;
    v2f q1 = b11 - d12*u10;
    v2f q2 = b21 - d12*u20;
    v2f n2 = q0*q0 + q1*q1 + q2*q2;
    v2f i2 = rsq2(n2);
    v2i ok2 = n2 > (v2f)1e-30f;
    i2 = sel2(ok2, i2, (v2f)0.0f);
    v2f u01 = q0*i2, u11 = q1*i2, u21 = q2*i2;

    v2f u02 = u10*u21 - u20*u11;
    v2f u12 = u20*u01 - u00*u21;
    v2f u22 = u00*u11 - u10*u01;

    r00 = u00*v00 + u01*v01 + u02*v02;
    r01 = u00*v10 + u01*v11 + u02*v12;
    r02 = u00*v20 + u01*v21 + u02*v22;
    r10 = u10*v00 + u11*v01 + u12*v02;
    r11 = u10*v10 + u11*v11 + u12*v12;
    r12 = u10*v20 + u11*v21 + u12*v22;
    r20 = u20*v00 + u21*v01 + u22*v02;
    r21 = u20*v10 + u21*v11 + u22*v12;
    r22 = u20*v20 + u21*v21 + u22*v22;
}

static __device__ __forceinline__ float4 ld_f4(const float* __restrict__ x, long f, long ntotf){
    if (f + 4 <= ntotf) return *(const float4*)(x + f);
    float4 r = make_float4(0.f, 0.f, 0.f, 0.f);
    if (f     < ntotf) r.x = x[f];
    if (f + 1 < ntotf) r.y = x[f + 1];
    if (f + 2 < ntotf) r.z = x[f + 2];
    if (f + 3 < ntotf) r.w = x[f + 3];
    return r;
}
static __device__ __forceinline__ void st_f4(float* __restrict__ o, long f, float4 v, long ntotf){
    if (f + 4 <= ntotf) { *(float4*)(o + f) = v; return; }
    if (f     < ntotf) o[f]     = v.x;
    if (f + 1 < ntotf) o[f + 1] = v.y;
    if (f + 2 < ntotf) o[f + 2] = v.z;
    if (f + 3 < ntotf) o[f + 3] = v.w;
}

// Wave-local SINGLE-buffer persistent pipeline. Exactly round 8's structure
// (which ran 33.5 us with NO launch-bounds cap and no spill), with the
// ping-pong second buffer removed — proven safe in round 9: the per-wave DS
// pipe is in-order, so iteration k's store-phase ds_reads complete before
// iteration k+1's landing ds_writes; the prefetched tile lives in q regs
// across compute. LDS 18.4 KB/block frees occupancy: grid 1536 -> ~6
// blocks/CU resident (VGPR-limited), 24 waves/CU vs round 8's 16.
// DO NOT add a min-waves launch bound: rounds 9/10 proved it spills the
// prefetch registers (FETCH/WRITE ballooned 35->58/70->117 MB).
__global__ __launch_bounds__(TPB) void svdo_kernel(const float* __restrict__ x,
                                                   float* __restrict__ out,
                                                   int nmat, int ntiles, int W)
{
    __shared__ float lds[4][FPW];       // 18432 B / block
    const int lane = threadIdx.x & 63;
    const int wv   = threadIdx.x >> 6;
    const long ntotf = (long)nmat * 9;

    int tile = blockIdx.x * 4 + wv;
    if (tile >= ntiles) return;

    float* L = lds[wv];

    float4 q0, q1, q2, q3, q4;
    {   // prologue: issue loads for first tile
        const long fb = (long)tile * FPW;
        q0 = ld_f4(x, fb + (long)(lane       ) * 4, ntotf);
        q1 = ld_f4(x, fb + (long)(lane +  64) * 4, ntotf);
        q2 = ld_f4(x, fb + (long)(lane + 128) * 4, ntotf);
        q3 = ld_f4(x, fb + (long)(lane + 192) * 4, ntotf);
        q4 = make_float4(0.f, 0.f, 0.f, 0.f);
        if (lane < 32) q4 = ld_f4(x, fb + (long)(lane + 256) * 4, ntotf);
    }

    for (;;) {
        // Land prefetched tile (counted vmcnt wait on the loads only; older
        // stores from iter k-1 keep draining in background).
        *(float4*)&L[(lane       ) * 4] = q0;
        *(float4*)&L[(lane +  64) * 4] = q1;
        *(float4*)&L[(lane + 128) * 4] = q2;
        *(float4*)&L[(lane + 192) * 4] = q3;
        if (lane < 32) *(float4*)&L[(lane + 256) * 4] = q4;
        asm volatile("s_waitcnt lgkmcnt(0)" ::: "memory");

        const int  nxt  = tile + W;
        const bool have = nxt < ntiles;
        if (have) {   // issue next tile's loads — in flight under compute
            const long fb = (long)nxt * FPW;
            q0 = ld_f4(x, fb + (long)(lane       ) * 4, ntotf);
            q1 = ld_f4(x, fb + (long)(lane +  64) * 4, ntotf);
            q2 = ld_f4(x, fb + (long)(lane + 128) * 4, ntotf);
            q3 = ld_f4(x, fb + (long)(lane + 192) * 4, ntotf);
            if (lane < 32) q4 = ld_f4(x, fb + (long)(lane + 256) * 4, ntotf);
        }

        // Compute 2 matrices (stride-9 LDS reads: 2 lanes/bank, free).
        {
            const float* p0 = &L[lane * 9];
            const float* p1 = &L[(lane + 64) * 9];
            v2f m00 = {p0[0], p1[0]}, m01 = {p0[1], p1[1]}, m02 = {p0[2], p1[2]};
            v2f m10 = {p0[3], p1[3]}, m11 = {p0[4], p1[4]}, m12 = {p0[5], p1[5]};
            v2f m20 = {p0[6], p1[6]}, m21 = {p0[7], p1[7]}, m22 = {p0[8], p1[8]};

            v2f r00, r01, r02, r10, r11, r12, r20, r21, r22;
            solve2(m00, m01, m02, m10, m11, m12, m20, m21, m22,
                   r00, r01, r02, r10, r11, r12, r20, r21, r22);

            float* o0 = &L[lane * 9];
            o0[0]=r00.x; o0[1]=r01.x; o0[2]=r02.x;
            o0[3]=r10.x; o0[4]=r11.x; o0[5]=r12.x;
            o0[6]=r20.x; o0[7]=r21.x; o0[8]=r22.x;
            float* o1 = &L[(lane + 64) * 9];
            o1[0]=r00.y; o1[1]=r01.y; o1[2]=r02.y;
            o1[3]=r10.y; o1[4]=r11.y; o1[5]=r12.y;
            o1[6]=r20.y; o1[7]=r21.y; o1[8]=r22.y;
        }
        asm volatile("s_waitcnt lgkmcnt(0)" ::: "memory");

        // Coalesced stores (fire-and-forget; never waited on in-loop).
        {
            const long fb = (long)tile * FPW;
            st_f4(out, fb + (long)(lane       ) * 4, *(const float4*)&L[(lane       ) * 4], ntotf);
            st_f4(out, fb + (long)(lane +  64) * 4, *(const float4*)&L[(lane +  64) * 4], ntotf);
            st_f4(out, fb + (long)(lane + 128) * 4, *(const float4*)&L[(lane + 128) * 4], ntotf);
            st_f4(out, fb + (long)(lane + 192) * 4, *(const float4*)&L[(lane + 192) * 4], ntotf);
            if (lane < 32)
                st_f4(out, fb + (long)(lane + 256) * 4, *(const float4*)&L[(lane + 256) * 4], ntotf);
        }

        if (!have) break;
        tile = nxt;
    }
}

extern "C" void kernel_launch(void* const* d_in, const int* in_sizes, int n_in,
                              void* d_out, int out_size, void* d_ws, size_t ws_size,
                              hipStream_t stream)
{
    (void)n_in; (void)d_ws; (void)ws_size; (void)out_size;
    const float* x = (const float*)d_in[0];
    float* out = (float*)d_out;
    const int nmat = in_sizes[0] / 9;
    const int ntiles = (nmat + MPW - 1) / MPW;
    int grid = (ntiles + 3) / 4;
    if (grid > 1536) grid = 1536;   // target ~6 blocks/CU (VGPR-limited), ~2.5 tiles/wave
    const int W = grid * 4;         // total waves = tile stride
    svdo_kernel<<<grid, TPB, 0, stream>>>(x, out, nmat, ntiles, W);
}